// Round 4
// baseline (206.614 us; speedup 1.0000x reference)
//
#include <hip/hip_runtime.h>

constexpr int Bn  = 1024;
constexpr int Tn  = 8192;
constexpr int Wn  = 2048;   // NUM_WORDS
constexpr int TPB = 512;
constexpr int CH  = 4;               // chunks per thread (processed in pairs)
constexpr int STRIDE = Tn / CH;      // 2048 elements per chunk region

// Per-position rule evaluation (matches the vectorized reference exactly):
//   INIT_TOKENS  = {94,122,100,92,43,27} -> INIT_DURS {2,3,2,2,5,5}
//   RATIO_TOKENS = {44,28,29,27,121,43}
__device__ __forceinline__ void rule_eval(float dp, float dpn, int tok, bool valid_next,
                                          float& g1, float& g2, float& sa) {
  float expected;
  bool in_init = true;
  switch (tok) {
    case 94:  expected = 2.f; break;
    case 122: expected = 3.f; break;
    case 100: expected = 2.f; break;
    case 92:  expected = 2.f; break;
    case 43:  expected = 5.f; break;
    case 27:  expected = 5.f; break;
    default:  expected = 0.f; in_init = false; break;
  }
  float t1 = dp - expected;
  bool fire1 = in_init && (t1 > 0.f);
  g1 = fire1 ? t1 : 0.f;
  bool in_ratio = (tok == 44) | (tok == 28) | (tok == 29) |
                  (tok == 27) | (tok == 121) | (tok == 43);
  bool fire2 = in_ratio && valid_next && (3.f * dp > dpn);
  g2 = fire2 ? (dp - dpn * (1.f / 3.f)) : 0.f;
  sa = fire2 ? g2 : (fire1 ? g1 : 0.f);
}

__device__ __forceinline__ float wave_reduce(float v) {
  #pragma unroll
  for (int o = 32; o > 0; o >>= 1) v += __shfl_down(v, o, 64);
  return v;
}

__global__ __launch_bounds__(TPB, 6) void loss_kernel(
    const float* __restrict__ dur_pred, const float* __restrict__ dur_gt,
    const int* __restrict__ ph2word, const int* __restrict__ txt,
    double* __restrict__ acc, unsigned int* __restrict__ cnt,
    float* __restrict__ out)
{
  __shared__ float wp[Wn];
  __shared__ float wg[Wn];
  __shared__ float sacc[5];   // pdur_s, rules_s, sp, sg, wd_s

  const int row = blockIdx.x;
  const size_t roff = (size_t)row * Tn;
  const float* __restrict__ dpr = dur_pred + roff;
  const float* __restrict__ dgr = dur_gt + roff;
  const int*   __restrict__ pwr = ph2word + roff;
  const int*   __restrict__ tkr = txt + roff;

  for (int i = threadIdx.x; i < Wn; i += TPB) { wp[i] = 0.f; wg[i] = 0.f; }
  if (threadIdx.x < 5) sacc[threadIdx.x] = 0.f;
  __syncthreads();

  float pdur_s = 0.f, rules_s = 0.f, sp = 0.f, sg = 0.f;
  const int lane = threadIdx.x & 63;
  const bool ll = (lane == 63);

  // Processes one 4-element chunk held entirely in registers.
  auto process = [&](float4 dp4, float4 dg4, int4 pw4, int4 tk4, int base) {
    // neighbor dp[base+4] via intra-wave shuffle; lane 63 loads (exec-masked)
    float dp_next = __shfl_down(dp4.x, 1, 64);
    float ext_dp4 = 0.f, ext_dp5 = 0.f;
    int ext_tk4 = -1;
    if (ll) {
      if (base + 4 < Tn) { ext_dp4 = dpr[base + 4]; ext_tk4 = tkr[base + 4]; }
      if (base + 5 < Tn) { ext_dp5 = dpr[base + 5]; }
      dp_next = ext_dp4;
    }

    float dpx[4] = {dp4.x, dp4.y, dp4.z, dp4.w};
    float dpn[4] = {dp4.y, dp4.z, dp4.w, dp_next};
    int   tkx[4] = {tk4.x, tk4.y, tk4.z, tk4.w};

    float g1[4], g2[4], sa[4], gsum[4];
    #pragma unroll
    for (int j = 0; j < 4; ++j) {
      rule_eval(dpx[j], dpn[j], tkx[j], (base + j) < Tn - 1, g1[j], g2[j], sa[j]);
      gsum[j] = g1[j] + g2[j];
    }

    // gsum at position base+4: next lane's gsum[0]; lane 63 computes its own
    float gnext = __shfl_down(gsum[0], 1, 64);
    if (ll) {
      if (base + 4 < Tn) {
        float e1, e2, es;
        rule_eval(ext_dp4, ext_dp5, ext_tk4, (base + 4) < Tn - 1, e1, e2, es);
        gnext = e1 + e2;
      } else {
        gnext = 0.f;
      }
    }
    float add[4] = {gsum[1], gsum[2], gsum[3],
                    (base + 3 < Tn - 1) ? gnext : 0.f};
    float dgl[4] = {dg4.x, dg4.y, dg4.z, dg4.w};

    #pragma unroll
    for (int j = 0; j < 4; ++j) {
      float dp = dpx[j];
      float dr = dp - sa[j] + add[j];          // dur_rules[i]
      float lp = __logf(dp + 1.f);
      float dlr = lp - __logf(dr + 1.f);
      rules_s += dlr * dlr;
      float dlg = lp - __logf(dgl[j] + 1.f);
      pdur_s += dlg * dlg;
      sp += fmaxf(dp, 0.f);
      sg += dgl[j];
    }

    // word segment sums: ph2word sorted per row -> run-compress, LDS atomics
    int pwl[4] = {pw4.x, pw4.y, pw4.z, pw4.w};
    int curw = pwl[0];
    float ap = 0.f, ag = 0.f;
    #pragma unroll
    for (int j = 0; j < 4; ++j) {
      if (pwl[j] != curw) {
        atomicAdd(&wp[curw], ap);
        atomicAdd(&wg[curw], ag);
        curw = pwl[j]; ap = 0.f; ag = 0.f;
      }
      ap += fmaxf(dpx[j], 0.f);
      ag += dgl[j];
    }
    atomicAdd(&wp[curw], ap);
    atomicAdd(&wg[curw], ag);
  };

  // Two super-iterations; each loads TWO chunks (8 vector loads in flight),
  // then computes both. unroll 1 keeps only one pair's buffers live.
  #pragma unroll 1
  for (int s = 0; s < CH / 2; ++s) {
    const int bA = (2 * s) * STRIDE + threadIdx.x * 4;
    const int bB = (2 * s + 1) * STRIDE + threadIdx.x * 4;

    float4 dpA = *reinterpret_cast<const float4*>(dpr + bA);
    float4 dgA = *reinterpret_cast<const float4*>(dgr + bA);
    int4   pwA = *reinterpret_cast<const int4*>(pwr + bA);
    int4   tkA = *reinterpret_cast<const int4*>(tkr + bA);
    float4 dpB = *reinterpret_cast<const float4*>(dpr + bB);
    float4 dgB = *reinterpret_cast<const float4*>(dgr + bB);
    int4   pwB = *reinterpret_cast<const int4*>(pwr + bB);
    int4   tkB = *reinterpret_cast<const int4*>(tkr + bB);

    process(dpA, dgA, pwA, tkA, bA);
    process(dpB, dgB, pwB, tkB, bB);
  }

  __syncthreads();

  // word-duration loss over words 1..Wn-1 (segment 0 dropped)
  float wd_s = 0.f;
  #pragma unroll
  for (int w = threadIdx.x; w < Wn; w += TPB) {
    if (w != 0) {
      float d = __logf(wp[w] + 1.f) - __logf(wg[w] + 1.f);
      wd_s += d * d;
    }
  }

  pdur_s  = wave_reduce(pdur_s);
  rules_s = wave_reduce(rules_s);
  sp      = wave_reduce(sp);
  sg      = wave_reduce(sg);
  wd_s    = wave_reduce(wd_s);
  if ((threadIdx.x & 63) == 0) {
    atomicAdd(&sacc[0], pdur_s);
    atomicAdd(&sacc[1], rules_s);
    atomicAdd(&sacc[2], sp);
    atomicAdd(&sacc[3], sg);
    atomicAdd(&sacc[4], wd_s);
  }
  __syncthreads();

  if (threadIdx.x == 0) {
    float ds = __logf(sacc[2] + 1.f) - __logf(sacc[3] + 1.f);
    double total = 0.6 * (double)sacc[0] / ((double)Bn * (double)Tn)
                 + 0.3 * (double)sacc[1] / ((double)Bn * (double)Tn)
                 + 0.3 * (double)sacc[4] / ((double)Bn * (double)(Wn - 1))
                 + 0.1 * (double)(ds * ds) / (double)Bn;
    atomicAdd(acc, total);
    __threadfence();
    unsigned int ticket = atomicAdd(cnt, 1u);
    if (ticket == (unsigned int)(Bn - 1)) {
      double final_val = atomicAdd(acc, 0.0);
      out[0] = (float)final_val;
    }
  }
}

extern "C" void kernel_launch(void* const* d_in, const int* in_sizes, int n_in,
                              void* d_out, int out_size, void* d_ws, size_t ws_size,
                              hipStream_t stream) {
  const float* dur_pred = (const float*)d_in[0];
  const float* dur_gt   = (const float*)d_in[1];
  const int*   ph2word  = (const int*)d_in[2];
  const int*   txt      = (const int*)d_in[3];
  double* acc = (double*)d_ws;
  unsigned int* cnt = (unsigned int*)((char*)d_ws + sizeof(double));

  hipMemsetAsync(d_ws, 0, 16, stream);
  loss_kernel<<<Bn, TPB, 0, stream>>>(dur_pred, dur_gt, ph2word, txt, acc, cnt,
                                      (float*)d_out);
}